// Round 1
// baseline (386.106 us; speedup 1.0000x reference)
//
#include <hip/hip_runtime.h>

#define B_DIM 8
#define C_DIM 128
#define N_SP 2304            // 48*48
#define NT 36                // N_SP / 64
#define NTRI ((NT * (NT + 1)) / 2)   // 666 upper-tri tiles

// ---------------- inverse column norms: r[t][b][n] = 1/(sqrt(sum_c x^2)+1e-8)
__global__ __launch_bounds__(256) void norms_kernel(
    const float* __restrict__ x0, const float* __restrict__ x1,
    const float* __restrict__ x2, const float* __restrict__ x3,
    float* __restrict__ rinv)
{
    int g = blockIdx.x * 256 + threadIdx.x;          // [0, 4*8*2304)
    int t = g / (B_DIM * N_SP);
    int rem = g - t * (B_DIM * N_SP);
    int b = rem / N_SP;
    int n = rem - b * N_SP;
    const float* x = (t == 0) ? x0 : (t == 1) ? x1 : (t == 2) ? x2 : x3;
    const float* col = x + (size_t)b * (C_DIM * N_SP) + n;
    float s = 0.0f;
#pragma unroll 8
    for (int c = 0; c < C_DIM; ++c) {
        float v = col[(size_t)c * N_SP];
        s = fmaf(v, v, s);
    }
    rinv[g] = 1.0f / (sqrtf(s) + 1e-8f);
}

// ---------------- fused Gram-diff over one 64x64 tile (out & tgt), upper-tri only
__global__ __launch_bounds__(256) void gram_diff_kernel(
    const float* __restrict__ o0, const float* __restrict__ o1,
    const float* __restrict__ t0, const float* __restrict__ t1,
    const float* __restrict__ rinv, float* __restrict__ accum)
{
    __shared__ float Ao[32][64];
    __shared__ float Bo[32][64];
    __shared__ float At[32][64];
    __shared__ float Bt[32][64];
    __shared__ float wred[4];

    int bid = blockIdx.x;
    int pair = bid / (B_DIM * NTRI);
    int rem  = bid - pair * (B_DIM * NTRI);
    int b    = rem / NTRI;
    int t    = rem - b * NTRI;
    int tn = 0, cnt = NT;
    while (t >= cnt) { t -= cnt; --cnt; ++tn; }
    int tm = tn + t;                                  // tn <= tm

    const float* xo = (pair == 0) ? o0 : o1;
    const float* xt = (pair == 0) ? t0 : t1;
    const float* xob = xo + (size_t)b * (C_DIM * N_SP);
    const float* xtb = xt + (size_t)b * (C_DIM * N_SP);
    const float* ro = rinv + (size_t)pair       * (B_DIM * N_SP) + (size_t)b * N_SP;
    const float* rt = rinv + (size_t)(pair + 2) * (B_DIM * N_SP) + (size_t)b * N_SP;

    int tid = threadIdx.x;
    int tx = tid & 15;        // 16 row-groups of 4
    int ty = tid >> 4;        // 16 col-groups of 4

    float acc_o[4][4] = {{0.f}};
    float acc_t[4][4] = {{0.f}};

    int c4 = tid & 15;        // staging: float4 column group
    int r0 = tid >> 4;        // staging: row 0..15

    for (int kk = 0; kk < C_DIM; kk += 32) {
#pragma unroll
        for (int p = 0; p < 2; ++p) {
            int row = r0 + p * 16;
            size_t roff = (size_t)(kk + row) * N_SP;
            *(float4*)&Ao[row][c4 * 4] = *(const float4*)(xob + roff + tn * 64 + c4 * 4);
            *(float4*)&Bo[row][c4 * 4] = *(const float4*)(xob + roff + tm * 64 + c4 * 4);
            *(float4*)&At[row][c4 * 4] = *(const float4*)(xtb + roff + tn * 64 + c4 * 4);
            *(float4*)&Bt[row][c4 * 4] = *(const float4*)(xtb + roff + tm * 64 + c4 * 4);
        }
        __syncthreads();
#pragma unroll 8
        for (int k = 0; k < 32; ++k) {
            float4 ao = *(const float4*)&Ao[k][tx * 4];
            float4 bo = *(const float4*)&Bo[k][ty * 4];
            float4 at = *(const float4*)&At[k][tx * 4];
            float4 bt = *(const float4*)&Bt[k][ty * 4];
            float a_[4] = {ao.x, ao.y, ao.z, ao.w};
            float b_[4] = {bo.x, bo.y, bo.z, bo.w};
            float c_[4] = {at.x, at.y, at.z, at.w};
            float d_[4] = {bt.x, bt.y, bt.z, bt.w};
#pragma unroll
            for (int i = 0; i < 4; ++i)
#pragma unroll
                for (int j = 0; j < 4; ++j) {
                    acc_o[i][j] = fmaf(a_[i], b_[j], acc_o[i][j]);
                    acc_t[i][j] = fmaf(c_[i], d_[j], acc_t[i][j]);
                }
        }
        __syncthreads();
    }

    // epilogue: apply inverse norms, abs-diff, weighted by symmetry
    float ron[4], rtn[4], rom[4], rtm[4];
#pragma unroll
    for (int i = 0; i < 4; ++i) {
        ron[i] = ro[tn * 64 + tx * 4 + i];
        rtn[i] = rt[tn * 64 + tx * 4 + i];
        rom[i] = ro[tm * 64 + ty * 4 + i];
        rtm[i] = rt[tm * 64 + ty * 4 + i];
    }
    float w = (tn == tm) ? 1.0f : 2.0f;
    float lsum = 0.0f;
#pragma unroll
    for (int i = 0; i < 4; ++i)
#pragma unroll
        for (int j = 0; j < 4; ++j) {
            float so = acc_o[i][j] * ron[i] * rom[j];
            float st = acc_t[i][j] * rtn[i] * rtm[j];
            lsum += fabsf(so - st);
        }
    lsum *= w;

    // block reduce: wave shuffle then cross-wave via LDS
#pragma unroll
    for (int off = 32; off > 0; off >>= 1) lsum += __shfl_down(lsum, off, 64);
    if ((tid & 63) == 0) wred[tid >> 6] = lsum;
    __syncthreads();
    if (tid == 0) atomicAdd(&accum[pair], wred[0] + wred[1] + wred[2] + wred[3]);
}

__global__ void finalize_kernel(const float* __restrict__ accum, float* __restrict__ out) {
    // each l1_loss is a mean over 8*2304*2304 elements
    out[0] = (accum[0] + accum[1]) * (1.0f / 42467328.0f);
}

extern "C" void kernel_launch(void* const* d_in, const int* in_sizes, int n_in,
                              void* d_out, int out_size, void* d_ws, size_t ws_size,
                              hipStream_t stream) {
    const float* o0 = (const float*)d_in[0];
    const float* o1 = (const float*)d_in[1];
    const float* t0 = (const float*)d_in[2];
    const float* t1 = (const float*)d_in[3];

    float* rinv  = (float*)d_ws;                       // 4*8*2304 = 73728 floats
    float* accum = rinv + 4 * B_DIM * N_SP;            // 2 floats

    hipMemsetAsync(accum, 0, 2 * sizeof(float), stream);

    norms_kernel<<<(4 * B_DIM * N_SP) / 256, 256, 0, stream>>>(o0, o1, t0, t1, rinv);

    int grid = 2 * B_DIM * NTRI;                       // 10656 tiles
    gram_diff_kernel<<<grid, 256, 0, stream>>>(o0, o1, t0, t1, rinv, accum);

    finalize_kernel<<<1, 1, 0, stream>>>(accum, (float*)d_out);
}

// Round 2
// 143.767 us; speedup vs baseline: 2.6856x; 2.6856x over previous
//
#include <hip/hip_runtime.h>
#include <hip/hip_bf16.h>
#include <stdint.h>

#define B_DIM 8
#define C_DIM 128
#define N_SP 2304
#define NT 18                     // 2304 / 128
#define NTRI 171                  // NT*(NT+1)/2

typedef __attribute__((ext_vector_type(8))) short short8;
typedef __attribute__((ext_vector_type(4))) float f32x4;

__device__ __forceinline__ uint32_t f2bf(float f) {
    uint32_t u = __float_as_uint(f);
    return (u + 0x7fffu + ((u >> 16) & 1u)) >> 16;    // RNE
}

// ---- prep: fp32 [C][N] -> bf16 [N][C] rows (16B chunks swizzled by n&7) + fp32 rinv
__global__ __launch_bounds__(256) void prep_kernel(
    const float* __restrict__ x0, const float* __restrict__ x1,
    const float* __restrict__ x2, const float* __restrict__ x3,
    ushort* __restrict__ xt, float* __restrict__ rinv)
{
    int bid = blockIdx.x;                 // 4 * 8 * 9 = 288
    int t  = bid / 72;
    int b  = (bid / 9) % 8;
    int n  = (bid % 9) * 256 + threadIdx.x;
    const float* x  = t == 0 ? x0 : t == 1 ? x1 : t == 2 ? x2 : x3;
    const float* xb = x + (size_t)b * (C_DIM * N_SP) + n;
    ushort* row = xt + ((size_t)(t * 8 + b) * N_SP + n) * 128;
    int sw = n & 7;
    float s = 0.f;
#pragma unroll
    for (int c = 0; c < 4; ++c) {         // 4 phases of 32 channels
        uint32_t w[16];
#pragma unroll
        for (int m = 0; m < 16; ++m) {
            float v0 = xb[(size_t)(c * 32 + 2 * m) * N_SP];
            float v1 = xb[(size_t)(c * 32 + 2 * m + 1) * N_SP];
            s = fmaf(v0, v0, s);
            s = fmaf(v1, v1, s);
            w[m] = f2bf(v0) | (f2bf(v1) << 16);
        }
#pragma unroll
        for (int j = 0; j < 4; ++j) {
            uint4 u; u.x = w[4*j]; u.y = w[4*j+1]; u.z = w[4*j+2]; u.w = w[4*j+3];
            *(uint4*)(row + (((c * 4 + j) ^ sw) * 8)) = u;
        }
    }
    rinv[(size_t)(t * 8 + b) * N_SP + n] = 1.f / (sqrtf(s) + 1e-8f);
}

// ---- fused Gram-diff: 128x128 S-tile, 4 waves x 64x64, bf16 MFMA
#define STAGE(xsrc, h)                                                              \
    {                                                                               \
        const ushort* sb = (wid & 2) ? (xsrc) + (size_t)tm * 16384                  \
                                     : (xsrc) + (size_t)tn * 16384;                 \
        ushort* pp = (wid & 2) ? pB : pA;                                           \
        int i0 = (wid & 1) * 8;                                                     \
        _Pragma("unroll")                                                           \
        for (int i = 0; i < 8; ++i) {                                               \
            int ii = i0 + i;                                                        \
            int col = ii * 8 + (lane >> 3);                                         \
            const ushort* src = sb + (size_t)col * 128 + (h) * 64 + (lane & 7) * 8; \
            __builtin_amdgcn_global_load_lds(                                       \
                (const __attribute__((address_space(1))) uint32_t*)src,             \
                (__attribute__((address_space(3))) uint32_t*)(pp + ii * 512),       \
                16, 0, 0);                                                          \
        }                                                                           \
    }

#define COMPUTE(ACC)                                                                \
    _Pragma("unroll")                                                               \
    for (int s = 0; s < 2; ++s) {                                                   \
        short8 av[4], bv[4];                                                        \
        int g = lane >> 4;                                                          \
        _Pragma("unroll")                                                           \
        for (int i = 0; i < 4; ++i) {                                               \
            int ca = wrow * 64 + i * 16 + (lane & 15);                              \
            av[i] = *(const short8*)&pA[ca * 64 + ((s * 4 + g) ^ (ca & 7)) * 8];    \
            int cb = wcol * 64 + i * 16 + (lane & 15);                              \
            bv[i] = *(const short8*)&pB[cb * 64 + ((s * 4 + g) ^ (cb & 7)) * 8];    \
        }                                                                           \
        _Pragma("unroll")                                                           \
        for (int i = 0; i < 4; ++i)                                                 \
            _Pragma("unroll")                                                       \
            for (int j = 0; j < 4; ++j)                                             \
                ACC[i][j] = __builtin_amdgcn_mfma_f32_16x16x32_bf16(                \
                    av[i], bv[j], ACC[i][j], 0, 0, 0);                              \
    }

__global__ __launch_bounds__(256, 2) void gram_kernel(
    const ushort* __restrict__ xt, const float* __restrict__ rinv,
    float* __restrict__ accum)
{
    __shared__ ushort pA[128 * 64];   // [128 cols][64 k] bf16, current K-half
    __shared__ ushort pB[128 * 64];
    __shared__ float rn[4][128];      // 0: o rows(tn) 1: o cols(tm) 2: t rows 3: t cols
    __shared__ float wred[4];

    int bid  = blockIdx.x;
    int pair = bid / (B_DIM * NTRI);
    int rem  = bid - pair * (B_DIM * NTRI);
    int b    = rem / NTRI;
    int t    = rem - b * NTRI;
    int tn = 0, cnt = NT;
    while (t >= cnt) { t -= cnt; --cnt; ++tn; }
    int tm = tn + t;

    const ushort* xo = xt + (size_t)(pair * 8 + b) * N_SP * 128;
    const ushort* xg = xt + (size_t)((pair + 2) * 8 + b) * N_SP * 128;
    const float*  ro = rinv + (size_t)(pair * 8 + b) * N_SP;
    const float*  rg = rinv + (size_t)((pair + 2) * 8 + b) * N_SP;

    int tid  = threadIdx.x;
    int wid  = tid >> 6;
    int lane = tid & 63;
    int wrow = wid >> 1, wcol = wid & 1;

    f32x4 acc_o[4][4], acc_t[4][4];
#pragma unroll
    for (int i = 0; i < 4; ++i)
#pragma unroll
        for (int j = 0; j < 4; ++j) {
            acc_o[i][j] = (f32x4){0.f, 0.f, 0.f, 0.f};
            acc_t[i][j] = (f32x4){0.f, 0.f, 0.f, 0.f};
        }

    STAGE(xo, 0);
    if (tid < 128) {
        rn[0][tid] = ro[tn * 128 + tid];
        rn[1][tid] = ro[tm * 128 + tid];
    } else {
        int q = tid - 128;
        rn[2][q] = rg[tn * 128 + q];
        rn[3][q] = rg[tm * 128 + q];
    }
    __syncthreads();
    COMPUTE(acc_o);
    __syncthreads();
    STAGE(xo, 1);
    __syncthreads();
    COMPUTE(acc_o);
    __syncthreads();
    STAGE(xg, 0);
    __syncthreads();
    COMPUTE(acc_t);
    __syncthreads();
    STAGE(xg, 1);
    __syncthreads();
    COMPUTE(acc_t);

    // epilogue: scale by inverse norms, abs-diff, reduce
    int fr = lane & 15, fq = lane >> 4;
    float co[4], cg[4];
#pragma unroll
    for (int j = 0; j < 4; ++j) {
        co[j] = rn[1][wcol * 64 + j * 16 + fr];
        cg[j] = rn[3][wcol * 64 + j * 16 + fr];
    }
    float w2 = (tn == tm) ? 1.f : 2.f;
    float lsum = 0.f;
#pragma unroll
    for (int i = 0; i < 4; ++i) {
#pragma unroll
        for (int r = 0; r < 4; ++r) {
            int rowl = wrow * 64 + i * 16 + fq * 4 + r;
            float ror = rn[0][rowl], rgr = rn[2][rowl];
#pragma unroll
            for (int j = 0; j < 4; ++j) {
                float so = acc_o[i][j][r] * ror * co[j];
                float st = acc_t[i][j][r] * rgr * cg[j];
                lsum += fabsf(so - st);
            }
        }
    }
    lsum *= w2;
#pragma unroll
    for (int off = 32; off > 0; off >>= 1) lsum += __shfl_down(lsum, off, 64);
    if (lane == 0) wred[wid] = lsum;
    __syncthreads();
    if (tid == 0) atomicAdd(&accum[pair], wred[0] + wred[1] + wred[2] + wred[3]);
}

__global__ void finalize_kernel(const float* __restrict__ a, float* __restrict__ out) {
    out[0] = (a[0] + a[1]) * (1.0f / 42467328.0f);   // mean over 8*2304*2304, x2 losses
}

extern "C" void kernel_launch(void* const* d_in, const int* in_sizes, int n_in,
                              void* d_out, int out_size, void* d_ws, size_t ws_size,
                              hipStream_t stream) {
    const float* o0 = (const float*)d_in[0];
    const float* o1 = (const float*)d_in[1];
    const float* t0 = (const float*)d_in[2];
    const float* t1 = (const float*)d_in[3];

    ushort* xtw  = (ushort*)d_ws;                                   // 18,874,368 B
    float*  rinv = (float*)((char*)d_ws + (size_t)4 * 8 * N_SP * 256);
    float*  accum = rinv + 4 * 8 * N_SP;

    hipMemsetAsync(accum, 0, 2 * sizeof(float), stream);
    prep_kernel<<<288, 256, 0, stream>>>(o0, o1, t0, t1, xtw, rinv);
    gram_kernel<<<2 * B_DIM * NTRI, 256, 0, stream>>>(xtw, rinv, accum);
    finalize_kernel<<<1, 1, 0, stream>>>(accum, (float*)d_out);
}

// Round 4
// 126.256 us; speedup vs baseline: 3.0581x; 1.1387x over previous
//
#include <hip/hip_runtime.h>
#include <hip/hip_bf16.h>
#include <stdint.h>

#define B_DIM 8
#define C_DIM 128
#define N_SP 2304
#define NT 18                     // 2304 / 128
#define NTRI 171                  // NT*(NT+1)/2
#define GRID_G (2 * B_DIM * NTRI) // 2736, divisible by 8

typedef __attribute__((ext_vector_type(8))) short short8;
typedef __attribute__((ext_vector_type(4))) float f32x4;

__device__ __forceinline__ uint32_t f2bf(float f) {
    uint32_t u = __float_as_uint(f);
    return (u + 0x7fffu + ((u >> 16) & 1u)) >> 16;    // RNE
}

// ---- prep: fp32 [C][N] -> bf16 [N][C] rows (16B chunks swizzled by n&7) + fp32 rinv
// 1152 blocks, 64 n per block, 4 threads per n. LDS-staged so global writes coalesce.
__global__ __launch_bounds__(256) void prep_kernel(
    const float* __restrict__ x0, const float* __restrict__ x1,
    const float* __restrict__ x2, const float* __restrict__ x3,
    ushort* __restrict__ xt, float* __restrict__ rinv)
{
    __shared__ ushort stage[64 * 128];    // 16 KB, final row layout (swizzled chunks)

    int bid = blockIdx.x;                 // 4 * 8 * 36
    int t  = bid / 288;
    int b  = (bid / 36) % 8;
    int nb = bid % 36;
    int tid = threadIdx.x;
    int q   = tid & 3;                    // c-quarter
    int nl  = tid >> 2;                   // local n 0..63
    int n   = nb * 64 + nl;
    const float* x  = t == 0 ? x0 : t == 1 ? x1 : t == 2 ? x2 : x3;
    const float* xb = x + (size_t)b * (C_DIM * N_SP) + n;
    int sw = nl & 7;

    float s = 0.f;
#pragma unroll
    for (int jj = 0; jj < 4; ++jj) {
        uint32_t w[4];
#pragma unroll
        for (int m = 0; m < 4; ++m) {
            int c = q * 32 + jj * 8 + m * 2;
            float v0 = xb[(size_t)c * N_SP];
            float v1 = xb[(size_t)(c + 1) * N_SP];
            s = fmaf(v0, v0, s);
            s = fmaf(v1, v1, s);
            w[m] = f2bf(v0) | (f2bf(v1) << 16);
        }
        int J = q * 4 + jj;
        uint4 u; u.x = w[0]; u.y = w[1]; u.z = w[2]; u.w = w[3];
        *(uint4*)&stage[nl * 128 + ((J ^ sw) * 8)] = u;
    }
    // norm reduce across the 4 lanes sharing n (lanes differ in bits 0-1)
    s += __shfl_xor(s, 1, 64);
    s += __shfl_xor(s, 2, 64);
    if (q == 0) rinv[(size_t)(t * 8 + b) * N_SP + n] = 1.f / (sqrtf(s) + 1e-8f);

    __syncthreads();
    ushort* dst = xt + ((size_t)(t * 8 + b) * N_SP + (size_t)nb * 64) * 128;
#pragma unroll
    for (int it = 0; it < 4; ++it)
        *(uint4*)(dst + it * 2048 + tid * 8) = *(const uint4*)(stage + it * 2048 + tid * 8);
}

// ---- fused Gram-diff: 128x128 S-tile, 4 waves x 64x64, bf16 MFMA, dbuf prefetch
#define STAGE(xsrc, h, PA, PB)                                                      \
    {                                                                               \
        const ushort* sb = (wid & 2) ? (xsrc) + (size_t)tm * 16384                  \
                                     : (xsrc) + (size_t)tn * 16384;                 \
        ushort* pp = (wid & 2) ? (PB) : (PA);                                       \
        int i0 = (wid & 1) * 8;                                                     \
        _Pragma("unroll")                                                           \
        for (int i = 0; i < 8; ++i) {                                               \
            int ii = i0 + i;                                                        \
            int col = ii * 8 + (lane >> 3);                                         \
            const ushort* src = sb + (size_t)col * 128 + (h) * 64 + (lane & 7) * 8; \
            __builtin_amdgcn_global_load_lds(                                       \
                (const __attribute__((address_space(1))) uint32_t*)src,             \
                (__attribute__((address_space(3))) uint32_t*)(pp + ii * 512),       \
                16, 0, 0);                                                          \
        }                                                                           \
    }

#define COMPUTE(ACC, PA, PB)                                                        \
    _Pragma("unroll")                                                               \
    for (int s = 0; s < 2; ++s) {                                                   \
        short8 av[4], bv[4];                                                        \
        int g = lane >> 4;                                                          \
        _Pragma("unroll")                                                           \
        for (int i = 0; i < 4; ++i) {                                               \
            int ca = wrow * 64 + i * 16 + (lane & 15);                              \
            av[i] = *(const short8*)&(PA)[ca * 64 + ((s * 4 + g) ^ (ca & 7)) * 8];  \
            int cb = wcol * 64 + i * 16 + (lane & 15);                              \
            bv[i] = *(const short8*)&(PB)[cb * 64 + ((s * 4 + g) ^ (cb & 7)) * 8];  \
        }                                                                           \
        _Pragma("unroll")                                                           \
        for (int i = 0; i < 4; ++i)                                                 \
            _Pragma("unroll")                                                       \
            for (int j = 0; j < 4; ++j)                                             \
                ACC[i][j] = __builtin_amdgcn_mfma_f32_16x16x32_bf16(                \
                    av[i], bv[j], ACC[i][j], 0, 0, 0);                              \
    }

__global__ __launch_bounds__(256, 2) void gram_kernel(
    const ushort* __restrict__ xt, const float* __restrict__ rinv,
    float* __restrict__ accum)
{
    __shared__ ushort pA[2][128 * 64];   // dbuf: [cols][64 k] per K-half
    __shared__ ushort pB[2][128 * 64];
    __shared__ float rn[4][128];
    __shared__ float wred[4];

    // XCD-aware bijective swizzle: chunk of 342 consecutive blocks per XCD
    int bid0 = blockIdx.x;
    int bid  = (bid0 & 7) * (GRID_G / 8) + (bid0 >> 3);

    int pair = bid / (B_DIM * NTRI);
    int rem  = bid - pair * (B_DIM * NTRI);
    int b    = rem / NTRI;
    int t    = rem - b * NTRI;
    int tn = 0, cnt = NT;
    while (t >= cnt) { t -= cnt; --cnt; ++tn; }
    int tm = tn + t;

    const ushort* xo = xt + (size_t)(pair * 8 + b) * N_SP * 128;
    const ushort* xg = xt + (size_t)((pair + 2) * 8 + b) * N_SP * 128;
    const float*  ro = rinv + (size_t)(pair * 8 + b) * N_SP;
    const float*  rg = rinv + (size_t)((pair + 2) * 8 + b) * N_SP;

    int tid  = threadIdx.x;
    int wid  = tid >> 6;
    int lane = tid & 63;
    int wrow = wid >> 1, wcol = wid & 1;

    f32x4 acc_o[4][4], acc_t[4][4];
#pragma unroll
    for (int i = 0; i < 4; ++i)
#pragma unroll
        for (int j = 0; j < 4; ++j) {
            acc_o[i][j] = (f32x4){0.f, 0.f, 0.f, 0.f};
            acc_t[i][j] = (f32x4){0.f, 0.f, 0.f, 0.f};
        }

    // ---- pipelined schedule: issue STAGE(r+1) before COMPUTE(r)
    STAGE(xo, 0, pA[0], pB[0]);
    if (tid < 128) {
        rn[0][tid] = ro[tn * 128 + tid];
        rn[1][tid] = ro[tm * 128 + tid];
    } else {
        int q = tid - 128;
        rn[2][q] = rg[tn * 128 + q];
        rn[3][q] = rg[tm * 128 + q];
    }
    __syncthreads();
    STAGE(xo, 1, pA[1], pB[1]);
    COMPUTE(acc_o, pA[0], pB[0]);
    __syncthreads();
    STAGE(xg, 0, pA[0], pB[0]);
    COMPUTE(acc_o, pA[1], pB[1]);
    __syncthreads();
    STAGE(xg, 1, pA[1], pB[1]);
    COMPUTE(acc_t, pA[0], pB[0]);
    __syncthreads();
    COMPUTE(acc_t, pA[1], pB[1]);

    // epilogue: scale by inverse norms, abs-diff, reduce
    int fr = lane & 15, fq = lane >> 4;
    float co[4], cg[4];
#pragma unroll
    for (int j = 0; j < 4; ++j) {
        co[j] = rn[1][wcol * 64 + j * 16 + fr];
        cg[j] = rn[3][wcol * 64 + j * 16 + fr];
    }
    float w2 = (tn == tm) ? 1.f : 2.f;
    float lsum = 0.f;
#pragma unroll
    for (int i = 0; i < 4; ++i) {
#pragma unroll
        for (int r = 0; r < 4; ++r) {
            int rowl = wrow * 64 + i * 16 + fq * 4 + r;
            float ror = rn[0][rowl], rgr = rn[2][rowl];
#pragma unroll
            for (int j = 0; j < 4; ++j) {
                float so = acc_o[i][j][r] * ror * co[j];
                float st = acc_t[i][j][r] * rgr * cg[j];
                lsum += fabsf(so - st);
            }
        }
    }
    lsum *= w2;
#pragma unroll
    for (int off = 32; off > 0; off >>= 1) lsum += __shfl_down(lsum, off, 64);
    if (lane == 0) wred[wid] = lsum;
    __syncthreads();
    if (tid == 0)
        atomicAdd(&accum[pair * 32 + (bid0 & 31)], wred[0] + wred[1] + wred[2] + wred[3]);
}

__global__ void finalize_kernel(const float* __restrict__ a, float* __restrict__ out) {
    float s = 0.f;
    for (int i = 0; i < 64; ++i) s += a[i];
    out[0] = s * (1.0f / 42467328.0f);   // mean over 8*2304*2304, two losses summed
}

extern "C" void kernel_launch(void* const* d_in, const int* in_sizes, int n_in,
                              void* d_out, int out_size, void* d_ws, size_t ws_size,
                              hipStream_t stream) {
    const float* o0 = (const float*)d_in[0];
    const float* o1 = (const float*)d_in[1];
    const float* t0 = (const float*)d_in[2];
    const float* t1 = (const float*)d_in[3];

    ushort* xtw  = (ushort*)d_ws;                                   // 18,874,368 B
    float*  rinv = (float*)((char*)d_ws + (size_t)4 * 8 * N_SP * 256);
    float*  accum = rinv + 4 * 8 * N_SP;                            // 64 floats

    hipMemsetAsync(accum, 0, 64 * sizeof(float), stream);
    prep_kernel<<<1152, 256, 0, stream>>>(o0, o1, t0, t1, xtw, rinv);
    gram_kernel<<<GRID_G, 256, 0, stream>>>(xtw, rinv, accum);
    finalize_kernel<<<1, 1, 0, stream>>>(accum, (float*)d_out);
}

// Round 5
// 121.494 us; speedup vs baseline: 3.1780x; 1.0392x over previous
//
#include <hip/hip_runtime.h>
#include <hip/hip_bf16.h>
#include <stdint.h>

#define B_DIM 8
#define C_DIM 128
#define N_SP 2304
#define NT 18                      // 2304 / 128
#define NTRI 171                   // NT*(NT+1)/2
#define NTILES (2 * B_DIM * NTRI)  // 2736 tiles
#define GRID_G (NTILES / 2)        // 1368 blocks, 2 tiles each; 1368 % 8 == 0

typedef __attribute__((ext_vector_type(8))) short short8;
typedef __attribute__((ext_vector_type(4))) float f32x4;

__device__ __forceinline__ uint32_t f2bf(float f) {
    uint32_t u = __float_as_uint(f);
    return (u + 0x7fffu + ((u >> 16) & 1u)) >> 16;    // RNE
}

// ---- prep: fp32 [C][N] -> bf16 [N][C] rows (16B chunks swizzled by n&7) + fp32 rinv
__global__ __launch_bounds__(256) void prep_kernel(
    const float* __restrict__ x0, const float* __restrict__ x1,
    const float* __restrict__ x2, const float* __restrict__ x3,
    ushort* __restrict__ xt, float* __restrict__ rinv, float* __restrict__ accum)
{
    __shared__ ushort stage[64 * 128];    // 16 KB

    int bid = blockIdx.x;                 // 4 * 8 * 36
    if (bid == 0 && threadIdx.x < 64) accum[threadIdx.x] = 0.f;   // replaces memset
    int t  = bid / 288;
    int b  = (bid / 36) % 8;
    int nb = bid % 36;
    int tid = threadIdx.x;
    int q   = tid & 3;                    // c-quarter
    int nl  = tid >> 2;                   // local n 0..63
    int n   = nb * 64 + nl;
    const float* x  = t == 0 ? x0 : t == 1 ? x1 : t == 2 ? x2 : x3;
    const float* xb = x + (size_t)b * (C_DIM * N_SP) + n;
    int sw = nl & 7;

    float s = 0.f;
#pragma unroll
    for (int jj = 0; jj < 4; ++jj) {
        uint32_t w[4];
#pragma unroll
        for (int m = 0; m < 4; ++m) {
            int c = q * 32 + jj * 8 + m * 2;
            float v0 = xb[(size_t)c * N_SP];
            float v1 = xb[(size_t)(c + 1) * N_SP];
            s = fmaf(v0, v0, s);
            s = fmaf(v1, v1, s);
            w[m] = f2bf(v0) | (f2bf(v1) << 16);
        }
        int J = q * 4 + jj;
        uint4 u; u.x = w[0]; u.y = w[1]; u.z = w[2]; u.w = w[3];
        *(uint4*)&stage[nl * 128 + ((J ^ sw) * 8)] = u;
    }
    s += __shfl_xor(s, 1, 64);
    s += __shfl_xor(s, 2, 64);
    if (q == 0) rinv[(size_t)(t * 8 + b) * N_SP + n] = 1.f / (sqrtf(s) + 1e-8f);

    __syncthreads();
    ushort* dst = xt + ((size_t)(t * 8 + b) * N_SP + (size_t)nb * 64) * 128;
#pragma unroll
    for (int it = 0; it < 4; ++it)
        *(uint4*)(dst + it * 2048 + tid * 8) = *(const uint4*)(stage + it * 2048 + tid * 8);
}

// ---- gram: 2 tiles per block, flat 8-round pipeline, bf16 MFMA
struct TileInfo {
    const ushort* xo; const ushort* xg;
    const float*  ro; const float*  rg;
    int tn, tm; float w2; int pair;
};

__device__ __forceinline__ TileInfo decode_tile(int g, const ushort* xt, const float* rinv) {
    int pair = g / (B_DIM * NTRI);
    int rem  = g - pair * (B_DIM * NTRI);
    int b    = rem / NTRI;
    int t    = rem - b * NTRI;
    int tn = 0, cnt = NT;
    while (t >= cnt) { t -= cnt; --cnt; ++tn; }
    TileInfo ti;
    ti.tn = tn; ti.tm = tn + t;
    ti.xo = xt + (size_t)(pair * 8 + b) * N_SP * 128;
    ti.xg = xt + (size_t)((pair + 2) * 8 + b) * N_SP * 128;
    ti.ro = rinv + (size_t)(pair * 8 + b) * N_SP;
    ti.rg = rinv + (size_t)((pair + 2) * 8 + b) * N_SP;
    ti.w2 = (tn == ti.tm) ? 1.f : 2.f;
    ti.pair = pair;
    return ti;
}

#define STAGE(sbase, TN, TM, h, PA, PB)                                             \
    {                                                                               \
        const ushort* sb = (wid & 2) ? (sbase) + (size_t)(TM) * 16384               \
                                     : (sbase) + (size_t)(TN) * 16384;              \
        ushort* pp = (wid & 2) ? (PB) : (PA);                                       \
        int i0 = (wid & 1) * 8;                                                     \
        _Pragma("unroll")                                                           \
        for (int i = 0; i < 8; ++i) {                                               \
            int ii = i0 + i;                                                        \
            int col = ii * 8 + (lane >> 3);                                         \
            const ushort* src = sb + (size_t)col * 128 + (h) * 64 + (lane & 7) * 8; \
            __builtin_amdgcn_global_load_lds(                                       \
                (const __attribute__((address_space(1))) uint32_t*)src,             \
                (__attribute__((address_space(3))) uint32_t*)(pp + ii * 512),       \
                16, 0, 0);                                                          \
        }                                                                           \
    }

#define COMPUTE(ACC, PA, PB)                                                        \
    _Pragma("unroll")                                                               \
    for (int s = 0; s < 2; ++s) {                                                   \
        short8 av[4], bv[4];                                                        \
        int g = lane >> 4;                                                          \
        _Pragma("unroll")                                                           \
        for (int i = 0; i < 4; ++i) {                                               \
            int ca = wrow * 64 + i * 16 + (lane & 15);                              \
            av[i] = *(const short8*)&(PA)[ca * 64 + ((s * 4 + g) ^ (ca & 7)) * 8];  \
            int cb = wcol * 64 + i * 16 + (lane & 15);                              \
            bv[i] = *(const short8*)&(PB)[cb * 64 + ((s * 4 + g) ^ (cb & 7)) * 8];  \
        }                                                                           \
        _Pragma("unroll")                                                           \
        for (int i = 0; i < 4; ++i)                                                 \
            _Pragma("unroll")                                                       \
            for (int j = 0; j < 4; ++j)                                             \
                ACC[i][j] = __builtin_amdgcn_mfma_f32_16x16x32_bf16(                \
                    av[i], bv[j], ACC[i][j], 0, 0, 0);                              \
    }

#define ZERO_ACC()                                                                  \
    _Pragma("unroll")                                                               \
    for (int i = 0; i < 4; ++i)                                                     \
        _Pragma("unroll")                                                           \
        for (int j = 0; j < 4; ++j) {                                               \
            acc_o[i][j] = (f32x4){0.f, 0.f, 0.f, 0.f};                              \
            acc_t[i][j] = (f32x4){0.f, 0.f, 0.f, 0.f};                              \
        }

// computes lsum from acc_o/acc_t with tile Q's norms, writes wred[wid]
#define EPILOGUE(Q, W2)                                                             \
    {                                                                               \
        int fr = lane & 15, fq = lane >> 4;                                         \
        float co[4], cg[4];                                                         \
        _Pragma("unroll")                                                           \
        for (int j = 0; j < 4; ++j) {                                               \
            co[j] = rn[Q][1][wcol * 64 + j * 16 + fr];                              \
            cg[j] = rn[Q][3][wcol * 64 + j * 16 + fr];                              \
        }                                                                           \
        float lsum = 0.f;                                                           \
        _Pragma("unroll")                                                           \
        for (int i = 0; i < 4; ++i) {                                               \
            _Pragma("unroll")                                                       \
            for (int r = 0; r < 4; ++r) {                                           \
                int rowl = wrow * 64 + i * 16 + fq * 4 + r;                         \
                float ror = rn[Q][0][rowl], rgr = rn[Q][2][rowl];                   \
                _Pragma("unroll")                                                   \
                for (int j = 0; j < 4; ++j) {                                       \
                    float so = acc_o[i][j][r] * ror * co[j];                        \
                    float st = acc_t[i][j][r] * rgr * cg[j];                        \
                    lsum += fabsf(so - st);                                         \
                }                                                                   \
            }                                                                       \
        }                                                                           \
        lsum *= (W2);                                                               \
        _Pragma("unroll")                                                           \
        for (int off = 32; off > 0; off >>= 1) lsum += __shfl_down(lsum, off, 64);  \
        if (lane == 0) wred[wid] = lsum;                                            \
    }

__global__ __launch_bounds__(256, 2) void gram_kernel(
    const ushort* __restrict__ xt, const float* __restrict__ rinv,
    float* __restrict__ accum)
{
    __shared__ ushort pA[2][128 * 64];
    __shared__ ushort pB[2][128 * 64];
    __shared__ float rn[2][4][128];
    __shared__ float wred[4];

    int bid0 = blockIdx.x;
    int bid  = (bid0 & 7) * (GRID_G / 8) + (bid0 >> 3);   // XCD chunking (bijective)

    TileInfo t0 = decode_tile(2 * bid,     xt, rinv);
    TileInfo t1 = decode_tile(2 * bid + 1, xt, rinv);

    int tid  = threadIdx.x;
    int wid  = tid >> 6;
    int lane = tid & 63;
    int wrow = wid >> 1, wcol = wid & 1;

    f32x4 acc_o[4][4], acc_t[4][4];
    ZERO_ACC();

    // r0 stage + norm loads
    STAGE(t0.xo, t0.tn, t0.tm, 0, pA[0], pB[0]);
    if (tid < 128) {
        rn[0][0][tid] = t0.ro[t0.tn * 128 + tid];
        rn[0][1][tid] = t0.ro[t0.tm * 128 + tid];
        rn[1][0][tid] = t1.ro[t1.tn * 128 + tid];
        rn[1][1][tid] = t1.ro[t1.tm * 128 + tid];
    } else {
        int u = tid - 128;
        rn[0][2][u] = t0.rg[t0.tn * 128 + u];
        rn[0][3][u] = t0.rg[t0.tm * 128 + u];
        rn[1][2][u] = t1.rg[t1.tn * 128 + u];
        rn[1][3][u] = t1.rg[t1.tm * 128 + u];
    }
    __syncthreads();
    STAGE(t0.xo, t0.tn, t0.tm, 1, pA[1], pB[1]);
    COMPUTE(acc_o, pA[0], pB[0]);
    __syncthreads();
    STAGE(t0.xg, t0.tn, t0.tm, 0, pA[0], pB[0]);
    COMPUTE(acc_o, pA[1], pB[1]);
    __syncthreads();
    STAGE(t0.xg, t0.tn, t0.tm, 1, pA[1], pB[1]);
    COMPUTE(acc_t, pA[0], pB[0]);
    __syncthreads();
    STAGE(t1.xo, t1.tn, t1.tm, 0, pA[0], pB[0]);
    COMPUTE(acc_t, pA[1], pB[1]);
    EPILOGUE(0, t0.w2);                       // tile0 done; overlaps t1 staging
    ZERO_ACC();
    __syncthreads();                          // buf0 ready; wred visible
    if (tid == 0)
        atomicAdd(&accum[t0.pair * 32 + (bid0 & 31)],
                  wred[0] + wred[1] + wred[2] + wred[3]);
    STAGE(t1.xo, t1.tn, t1.tm, 1, pA[1], pB[1]);
    COMPUTE(acc_o, pA[0], pB[0]);
    __syncthreads();
    STAGE(t1.xg, t1.tn, t1.tm, 0, pA[0], pB[0]);
    COMPUTE(acc_o, pA[1], pB[1]);
    __syncthreads();
    STAGE(t1.xg, t1.tn, t1.tm, 1, pA[1], pB[1]);
    COMPUTE(acc_t, pA[0], pB[0]);
    __syncthreads();
    COMPUTE(acc_t, pA[1], pB[1]);
    EPILOGUE(1, t1.w2);
    __syncthreads();
    if (tid == 0)
        atomicAdd(&accum[t1.pair * 32 + (bid0 & 31)],
                  wred[0] + wred[1] + wred[2] + wred[3]);
}

__global__ void finalize_kernel(const float* __restrict__ a, float* __restrict__ out) {
    float s = a[threadIdx.x];
#pragma unroll
    for (int off = 32; off > 0; off >>= 1) s += __shfl_down(s, off, 64);
    if (threadIdx.x == 0) out[0] = s * (1.0f / 42467328.0f);
}

extern "C" void kernel_launch(void* const* d_in, const int* in_sizes, int n_in,
                              void* d_out, int out_size, void* d_ws, size_t ws_size,
                              hipStream_t stream) {
    const float* o0 = (const float*)d_in[0];
    const float* o1 = (const float*)d_in[1];
    const float* t0 = (const float*)d_in[2];
    const float* t1 = (const float*)d_in[3];

    ushort* xtw  = (ushort*)d_ws;                                   // 18,874,368 B
    float*  rinv = (float*)((char*)d_ws + (size_t)4 * 8 * N_SP * 256);
    float*  accum = rinv + 4 * 8 * N_SP;                            // 64 floats

    prep_kernel<<<1152, 256, 0, stream>>>(o0, o1, t0, t1, xtw, rinv, accum);
    gram_kernel<<<GRID_G, 256, 0, stream>>>(xtw, rinv, accum);
    finalize_kernel<<<1, 64, 0, stream>>>(accum, (float*)d_out);
}